// Round 9
// baseline (251.555 us; speedup 1.0000x reference)
//
#include <hip/hip_runtime.h>

// Problem constants (match reference setup_inputs)
constexpr int Bc   = 8;
constexpr int Nc   = 2048;   // power of two: global row = b*Nc + i
constexpr int DIN  = 5;
constexpr int DHID = 32;

// clang vector type usable with __builtin_nontemporal_store
typedef float vf4 __attribute__((ext_vector_type(4)));

// ---------------------------------------------------------------------------
// Kernel 1: u[b, d, j] = sum_e M[d][e] * s[b, j, e],  M = Qw @ Kw^T (5x5)
// Layout [B][DIN][N] -> coalesced float4 streams in the main kernel.
// ---------------------------------------------------------------------------
__global__ __launch_bounds__(256) void u_precompute(
    const float* __restrict__ s, const float* __restrict__ Qw,
    const float* __restrict__ Kw, float* __restrict__ u)
{
    __shared__ float Msh[DIN * DIN];
    const int tid = threadIdx.x;
    if (tid < DIN * DIN) {
        const int d = tid / DIN, e = tid % DIN;
        float acc = 0.f;
        #pragma unroll
        for (int m = 0; m < DHID; ++m)
            acc = fmaf(Qw[d * DHID + m], Kw[e * DHID + m], acc);
        Msh[tid] = acc;
    }
    __syncthreads();
    const int g = blockIdx.x * 256 + tid;       // g in [0, B*N)
    if (g >= Bc * Nc) return;
    const int b = g >> 11;
    const int j = g & (Nc - 1);
    float sv[DIN];
    #pragma unroll
    for (int e = 0; e < DIN; ++e) sv[e] = s[(size_t)g * DIN + e];
    #pragma unroll
    for (int d = 0; d < DIN; ++d) {
        float acc = 0.f;
        #pragma unroll
        for (int e = 0; e < DIN; ++e) acc = fmaf(Msh[d * DIN + e], sv[e], acc);
        u[((size_t)b * DIN + d) * Nc + j] = acc;
    }
}

// ---------------------------------------------------------------------------
// Main kernel v3: ONE WAVE = ONE ROW. 4 independent waves per 256-thread
// block; no __syncthreads, no LDS. Each lane owns 32 j's (8 float4).
// All 8 G-loads issue up front (deep MLP); u streams are L1/L2-resident
// (40 KB per batch slice, shared by 2048 rows). Row-sum is a pure 6-step
// wave64 shuffle reduce; att values stay in registers; one NT-store pass.
// ---------------------------------------------------------------------------
__global__ __launch_bounds__(256) void att_wave_row(
    const float* __restrict__ s, const float* __restrict__ G,
    const float* __restrict__ u, float* __restrict__ out, long gbs)
{
    const int tid  = threadIdx.x;
    const int lane = tid & 63;
    const int wid  = tid >> 6;
    const int row  = blockIdx.x * 4 + wid;       // global row = b*Nc + i
    const int b    = row >> 11;
    const int i    = row & (Nc - 1);

    const float* gRow = G + (size_t)b * gbs + (size_t)i * Nc;
    const float* ub   = u + (size_t)b * DIN * Nc;
    float*       oRow = out + (size_t)row * Nc;

    // s_i (wave-uniform scalar loads)
    float si[DIN];
    #pragma unroll
    for (int d = 0; d < DIN; ++d) si[d] = s[(size_t)row * DIN + d];

    // issue all 8 G loads up front — 32 VGPRs of payload in flight
    float4 g4[8];
    #pragma unroll
    for (int k = 0; k < 8; ++k)
        g4[k] = *reinterpret_cast<const float4*>(gRow + k * 256 + lane * 4);

    float a[8][4];
    float psum = 0.f;
    #pragma unroll
    for (int k = 0; k < 8; ++k) {
        const int j0 = k * 256 + lane * 4;
        float vx = 0.f, vy = 0.f, vz = 0.f, vw = 0.f;
        #pragma unroll
        for (int d = 0; d < DIN; ++d) {
            const float4 u4 = *reinterpret_cast<const float4*>(ub + (size_t)d * Nc + j0);
            vx = fmaf(si[d], u4.x, vx);
            vy = fmaf(si[d], u4.y, vy);
            vz = fmaf(si[d], u4.z, vz);
            vw = fmaf(si[d], u4.w, vw);
        }
        a[k][0] = vx * vx * g4[k].x;
        a[k][1] = vy * vy * g4[k].y;
        a[k][2] = vz * vz * g4[k].z;
        a[k][3] = vw * vw * g4[k].w;
        psum += (a[k][0] + a[k][1]) + (a[k][2] + a[k][3]);
    }

    // wave64 butterfly reduce — no LDS, no barrier
    #pragma unroll
    for (int off = 32; off > 0; off >>= 1)
        psum += __shfl_xor(psum, off, 64);
    const float inv = 1.0f / (psum + 0.001f);

    #pragma unroll
    for (int k = 0; k < 8; ++k) {
        const int j0 = k * 256 + lane * 4;
        vf4 o;
        o.x = a[k][0] * inv;
        o.y = a[k][1] * inv;
        o.z = a[k][2] * inv;
        o.w = a[k][3] * inv;
        __builtin_nontemporal_store(o, reinterpret_cast<vf4*>(oRow + j0));
    }
}

// ---------------------------------------------------------------------------
// Fallback (no workspace): single-row blocks, M computed per block.
// ---------------------------------------------------------------------------
__global__ __launch_bounds__(256) void att_row_direct(
    const float* __restrict__ s, const float* __restrict__ G,
    const float* __restrict__ Qw, const float* __restrict__ Kw,
    float* __restrict__ out, long gbs)
{
    __shared__ float Msh[DIN * DIN];
    __shared__ float wpart[4];
    const int tid = threadIdx.x;
    if (tid < DIN * DIN) {
        const int d = tid / DIN, e = tid % DIN;
        float acc = 0.f;
        #pragma unroll
        for (int m = 0; m < DHID; ++m)
            acc = fmaf(Qw[d * DHID + m], Kw[e * DHID + m], acc);
        Msh[tid] = acc;
    }
    __syncthreads();

    const int row = blockIdx.x;
    const int b   = row >> 11;
    const int i   = row & (Nc - 1);

    float w[DIN];
    {
        float si[DIN];
        #pragma unroll
        for (int e = 0; e < DIN; ++e) si[e] = s[(size_t)row * DIN + e];
        #pragma unroll
        for (int d = 0; d < DIN; ++d) {
            float acc = 0.f;
            #pragma unroll
            for (int e = 0; e < DIN; ++e) acc = fmaf(si[e], Msh[e * DIN + d], acc);
            w[d] = acc;
        }
    }

    const float* gRow = G + (size_t)b * gbs + (size_t)i * Nc;
    const float* sb   = s + (size_t)b * Nc * DIN;
    float*       oRow = out + (size_t)row * Nc;

    float a[2][4];
    float lsum = 0.f;
    #pragma unroll
    for (int it = 0; it < 2; ++it) {
        const int j0 = it * 1024 + tid * 4;
        const float4 g4 = *reinterpret_cast<const float4*>(gRow + j0);
        float v[4];
        #pragma unroll
        for (int c = 0; c < 4; ++c) {
            const float* sj = sb + (size_t)(j0 + c) * DIN;
            float acc = 0.f;
            #pragma unroll
            for (int d = 0; d < DIN; ++d) acc = fmaf(w[d], sj[d], acc);
            v[c] = acc;
        }
        a[it][0] = v[0] * v[0] * g4.x;
        a[it][1] = v[1] * v[1] * g4.y;
        a[it][2] = v[2] * v[2] * g4.z;
        a[it][3] = v[3] * v[3] * g4.w;
        lsum += (a[it][0] + a[it][1]) + (a[it][2] + a[it][3]);
    }

    #pragma unroll
    for (int off = 32; off > 0; off >>= 1)
        lsum += __shfl_xor(lsum, off, 64);
    if ((tid & 63) == 0) wpart[tid >> 6] = lsum;
    __syncthreads();
    const float total = (wpart[0] + wpart[1]) + (wpart[2] + wpart[3]);
    const float inv = 1.0f / (total + 0.001f);

    #pragma unroll
    for (int it = 0; it < 2; ++it) {
        const int j0 = it * 1024 + tid * 4;
        vf4 o;
        o.x = a[it][0] * inv;
        o.y = a[it][1] * inv;
        o.z = a[it][2] * inv;
        o.w = a[it][3] * inv;
        __builtin_nontemporal_store(o, reinterpret_cast<vf4*>(oRow + j0));
    }
}

extern "C" void kernel_launch(void* const* d_in, const int* in_sizes, int n_in,
                              void* d_out, int out_size, void* d_ws, size_t ws_size,
                              hipStream_t stream)
{
    const float* s  = (const float*)d_in[0];
    const float* G  = (const float*)d_in[1];
    const float* Qw = (const float*)d_in[2];
    const float* Kw = (const float*)d_in[3];
    float* out = (float*)d_out;

    // Gmat may be [N,N] (broadcast) or [B,N,N]
    const long gbs = (in_sizes[1] == Nc * Nc) ? 0L : (long)Nc * Nc;

    const size_t uBytes = (size_t)Bc * DIN * Nc * sizeof(float);
    if (ws_size >= uBytes) {
        float* u = (float*)d_ws;
        u_precompute<<<(Bc * Nc + 255) / 256, 256, 0, stream>>>(s, Qw, Kw, u);
        att_wave_row<<<(Bc * Nc) / 4, 256, 0, stream>>>(s, G, u, out, gbs);
    } else {
        att_row_direct<<<Bc * Nc, 256, 0, stream>>>(s, G, Qw, Kw, out, gbs);
    }
}